// Round 2
// baseline (400.108 us; speedup 1.0000x reference)
//
#include <hip/hip_runtime.h>
#include <hip/hip_bf16.h>

typedef __bf16 bf16_t;
typedef __bf16 bf16x8 __attribute__((ext_vector_type(8)));
typedef float f32x4 __attribute__((ext_vector_type(4)));

// ---------------------------------------------------------------------------
// async global->LDS, 16B per lane (dest must be wave-uniform base + lane*16)
__device__ __forceinline__ void gload_lds16(const void* g, void* l) {
  __builtin_amdgcn_global_load_lds((const __attribute__((address_space(1))) void*)g,
                                   (__attribute__((address_space(3))) void*)l, 16, 0, 0);
}

// ---------------------------------------------------------------------------
// fp32 -> bf16 cast, 8 elements/thread
__global__ __launch_bounds__(256) void cvt_bf16_kernel(const float* __restrict__ src,
                                                       bf16_t* __restrict__ dst, int n8) {
  int i = blockIdx.x * 256 + threadIdx.x;
  if (i >= n8) return;
  const float4* s4 = (const float4*)src;
  float4 a = s4[2 * i], b = s4[2 * i + 1];
  bf16x8 o;
  o[0] = (bf16_t)a.x; o[1] = (bf16_t)a.y; o[2] = (bf16_t)a.z; o[3] = (bf16_t)a.w;
  o[4] = (bf16_t)b.x; o[5] = (bf16_t)b.y; o[6] = (bf16_t)b.z; o[7] = (bf16_t)b.w;
  *(bf16x8*)(dst + 8 * (size_t)i) = o;
}

// ---------------------------------------------------------------------------
// fp32 [R][C] -> bf16 [C][R]  (weights: store W^T so GEMM B-staging is linear)
__global__ __launch_bounds__(256) void trcvt_kernel(const float* __restrict__ src,
                                                    bf16_t* __restrict__ dst, int R, int C) {
  __shared__ float tile[32][33];
  int c0 = blockIdx.x * 32, r0 = blockIdx.y * 32;
  int tx = threadIdx.x, ty = threadIdx.y;
#pragma unroll
  for (int i = 0; i < 4; ++i)
    tile[ty + i * 8][tx] = src[(size_t)(r0 + ty + i * 8) * C + c0 + tx];
  __syncthreads();
#pragma unroll
  for (int i = 0; i < 4; ++i)
    dst[(size_t)(c0 + ty + i * 8) * R + r0 + tx] = (bf16_t)tile[tx][ty + i * 8];
}

// bf16 [R][C] -> bf16 [C][R]  (V -> V^T for the PV B-operand)
__global__ __launch_bounds__(256) void trb_kernel(const bf16_t* __restrict__ src,
                                                  bf16_t* __restrict__ dst, int R, int C) {
  __shared__ bf16_t tile[32][33];
  int c0 = blockIdx.x * 32, r0 = blockIdx.y * 32;
  int tx = threadIdx.x, ty = threadIdx.y;
#pragma unroll
  for (int i = 0; i < 4; ++i)
    tile[ty + i * 8][tx] = src[(size_t)(r0 + ty + i * 8) * C + c0 + tx];
  __syncthreads();
#pragma unroll
  for (int i = 0; i < 4; ++i)
    dst[(size_t)(c0 + ty + i * 8) * R + r0 + tx] = tile[tx][ty + i * 8];
}

// ---------------------------------------------------------------------------
// RoPE tables: cos/sin[s][d], d in [0,64), angle = s * 10000^(-d/64)
__global__ __launch_bounds__(256) void rope_tab_kernel(float* __restrict__ cosT,
                                                       float* __restrict__ sinT) {
  int i = blockIdx.x * 256 + threadIdx.x;  // 2048*64
  int s = i >> 6, d = i & 63;
  float ang = (float)s * powf(10000.0f, -(float)d * (1.0f / 64.0f));
  cosT[i] = cosf(ang);
  sinT[i] = sinf(ang);
}

// ---------------------------------------------------------------------------
// GEMM  C[M,N] = A[M,K] @ B[K,N], B given transposed (Bt[N][K], ld=K=4096).
// 128x128 tile, BK=64, 4 waves each 32x128 (full head width -> register RoPE).
// MODE 0: fused QKV projection (N=6144 via B0=Wq^T rows 0..4095, B1=WkWv^T),
//         epilogue: RoPE+scale->Qb, RoPE->Kb, plain->Vb (all bf16).
// MODE 1: out-projection, fp32 stores to Cout.
template <int MODE>
__global__ __launch_bounds__(256, 2) void gemm_bt_kernel(
    const bf16_t* __restrict__ A, const bf16_t* __restrict__ B0,
    const bf16_t* __restrict__ B1, const float* __restrict__ cosT,
    const float* __restrict__ sinT, bf16_t* __restrict__ Qb,
    bf16_t* __restrict__ Kb, bf16_t* __restrict__ Vb, float* __restrict__ Cout) {
  constexpr int K = 4096;
  constexpr int MT = 16;
  __shared__ alignas(16) unsigned char sAB[32768];
  unsigned char* sA = sAB;
  unsigned char* sB = sAB + 16384;
  const int bx = blockIdx.x;
  const int mt = bx % MT, nt = bx / MT;
  const int bm = mt * 128;
  const bf16_t* Bt;
  if (MODE == 0)
    Bt = (nt < 32) ? (B0 + (size_t)nt * 128 * K) : (B1 + (size_t)(nt - 32) * 128 * K);
  else
    Bt = B0 + (size_t)nt * 128 * K;

  const int t = threadIdx.x;
  // staging: LDS tiles [128 rows][64 ele] (128B rows), XOR-swizzled source cols
  const int sr = t >> 3;                         // row step within pass (32/pass)
  const int scol = ((t & 7) ^ (sr & 7)) * 8;     // pre-swizzled global col (elems)
  const bf16_t* aG = A + (size_t)(bm + sr) * K + scol;
  const bf16_t* bG = Bt + (size_t)sr * K + scol;
  unsigned char* aL = sA + t * 16;
  unsigned char* bL = sB + t * 16;

  const int lane = t & 63, w = t >> 6;
  const int lr = lane & 15, lq = lane >> 4;
  const int swz = (lr & 7) << 4;

  f32x4 acc[2][8];
#pragma unroll
  for (int m = 0; m < 2; ++m)
#pragma unroll
    for (int n = 0; n < 8; ++n) acc[m][n] = f32x4{0.f, 0.f, 0.f, 0.f};

  for (int k0 = 0; k0 < K; k0 += 64) {
    __syncthreads();
#pragma unroll
    for (int p = 0; p < 4; ++p) {
      gload_lds16(aG + (size_t)(p * 32) * K + k0, aL + p * 4096);
      gload_lds16(bG + (size_t)(p * 32) * K + k0, bL + p * 4096);
    }
    __syncthreads();
#pragma unroll
    for (int kk = 0; kk < 2; ++kk) {
      bf16x8 af[2], bfr[8];
#pragma unroll
      for (int m = 0; m < 2; ++m)
        af[m] = *(const bf16x8*)(sA + (w * 32 + m * 16 + lr) * 128 +
                                 ((kk * 64 + lq * 16) ^ swz));
#pragma unroll
      for (int n = 0; n < 8; ++n)
        bfr[n] = *(const bf16x8*)(sB + (n * 16 + lr) * 128 +
                                  ((kk * 64 + lq * 16) ^ swz));
#pragma unroll
      for (int m = 0; m < 2; ++m)
#pragma unroll
        for (int n = 0; n < 8; ++n)
          acc[m][n] = __builtin_amdgcn_mfma_f32_16x16x32_bf16(af[m], bfr[n],
                                                              acc[m][n], 0, 0, 0);
    }
  }

  // epilogue: C frag mapping col = lane&15, row = (lane>>4)*4 + reg
  if (MODE == 1) {
#pragma unroll
    for (int m = 0; m < 2; ++m)
#pragma unroll
      for (int n = 0; n < 8; ++n)
#pragma unroll
        for (int r = 0; r < 4; ++r)
          Cout[(size_t)(bm + w * 32 + m * 16 + lq * 4 + r) * 4096 + nt * 128 +
               n * 16 + lr] = acc[m][n][r];
  } else {
    const bool isQ = nt < 32;
    const bool isK = (nt >= 32) && (nt < 40);
    if (isQ || isK) {
      bf16_t* dst = isQ ? Qb : Kb;
      const int ld = isQ ? 4096 : 1024;
      const int col0 = isQ ? nt * 128 : (nt - 32) * 128;
      const float qs = isQ ? 0.08838834764831845f : 1.0f;  // fold 1/sqrt(128) into Q
#pragma unroll
      for (int m = 0; m < 2; ++m)
#pragma unroll
        for (int n = 0; n < 4; ++n)
#pragma unroll
          for (int r = 0; r < 4; ++r) {
            int srow = bm + w * 32 + m * 16 + lq * 4 + r;
            int d = n * 16 + lr;  // 0..63; pair d+64 is frag n+4 (same lane)
            float c = cosT[srow * 64 + d], s = sinT[srow * 64 + d];
            float x1 = acc[m][n][r], x2 = acc[m][n + 4][r];
            dst[(size_t)srow * ld + col0 + d] = (bf16_t)((x1 * c - x2 * s) * qs);
            dst[(size_t)srow * ld + col0 + d + 64] = (bf16_t)((x2 * c + x1 * s) * qs);
          }
    } else {
      const int col0 = (nt - 40) * 128;
#pragma unroll
      for (int m = 0; m < 2; ++m)
#pragma unroll
        for (int n = 0; n < 8; ++n)
#pragma unroll
          for (int r = 0; r < 4; ++r)
            Vb[(size_t)(bm + w * 32 + m * 16 + lq * 4 + r) * 1024 + col0 +
               n * 16 + lr] = (bf16_t)acc[m][n][r];
    }
  }
}

// ---------------------------------------------------------------------------
// Flash attention: block = 1 (head, 64-row q-tile), 4 waves x 16 q-rows.
// K-tile 64x128 and V^T-tile 128x64 staged in swizzled LDS; online softmax.
// Kb layout: [2048 s][8 kv-heads * 128]  (ld = 1024, col offset kvh*128)
__global__ __launch_bounds__(256, 2) void attn_kernel(
    const bf16_t* __restrict__ Qb, const bf16_t* __restrict__ Kb,
    const bf16_t* __restrict__ Vt, const float* __restrict__ mask,
    bf16_t* __restrict__ Ob) {
  __shared__ alignas(16) unsigned char sMem[40960];
  unsigned char* sK = sMem;          // 16KB: [64 sk][128 d]
  unsigned char* sV = sMem + 16384;  // 16KB: [128 d][64 sk]
  unsigned char* sP = sMem + 32768;  // 4 waves * 2KB: P[16][64]
  const int bx = blockIdx.x;
  const int h = bx >> 5, qt = bx & 31;
  const int kvh = h >> 2;
  const int q0 = qt * 64;
  const int t = threadIdx.x, lane = t & 63, w = t >> 6;
  const int lr = lane & 15, lq = lane >> 4;
  const int swz = (lr & 7) << 4;

  // Q fragments in registers (already RoPE'd and pre-scaled by 1/sqrt(128))
  bf16x8 qf[4];
#pragma unroll
  for (int kk = 0; kk < 4; ++kk)
    qf[kk] = *(const bf16x8*)(Qb + (size_t)(q0 + w * 16 + lr) * 4096 + h * 128 +
                              kk * 32 + lq * 8);

  const int srK = t >> 4;
  const int scK = ((t & 15) ^ (srK & 7)) * 8;
  const bf16_t* kG = Kb + (size_t)srK * 1024 + kvh * 128 + scK;  // ld=1024 + head off
  const int srV = t >> 3;
  const int scV = ((t & 7) ^ (srV & 7)) * 8;
  const bf16_t* vG = Vt + (size_t)(kvh * 128 + srV) * 2048 + scV;
  unsigned char* kL = sK + t * 16;
  unsigned char* vL = sV + t * 16;
  unsigned char* sPw = sP + w * 2048;

  f32x4 o[8];
#pragma unroll
  for (int n = 0; n < 8; ++n) o[n] = f32x4{0.f, 0.f, 0.f, 0.f};
  float mrun[4], lrun[4];
#pragma unroll
  for (int r = 0; r < 4; ++r) { mrun[r] = -1e30f; lrun[r] = 0.f; }

  for (int kt = 0; kt < 32; ++kt) {
    __syncthreads();
#pragma unroll
    for (int p = 0; p < 4; ++p) {
      gload_lds16(kG + (size_t)(kt * 64 + p * 16) * 1024, kL + p * 4096);
      gload_lds16(vG + (size_t)(p * 32) * 2048 + kt * 64, vL + p * 4096);
    }
    __syncthreads();

    // S = Q K^T (rows = q, cols = sk)
    f32x4 scf[4];
#pragma unroll
    for (int n = 0; n < 4; ++n) scf[n] = f32x4{0.f, 0.f, 0.f, 0.f};
#pragma unroll
    for (int kk = 0; kk < 4; ++kk)
#pragma unroll
      for (int n = 0; n < 4; ++n) {
        bf16x8 b = *(const bf16x8*)(sK + (n * 16 + lr) * 256 +
                                    ((kk * 64 + lq * 16) ^ swz));
        scf[n] = __builtin_amdgcn_mfma_f32_16x16x32_bf16(qf[kk], b, scf[n], 0, 0, 0);
      }
    // + attention mask (broadcast over q)
#pragma unroll
    for (int n = 0; n < 4; ++n) {
      float mk = mask[kt * 64 + n * 16 + lr];
#pragma unroll
      for (int r = 0; r < 4; ++r) scf[n][r] += mk;
    }
    // online softmax (row = lq*4 + r lives in the 16-lane group sharing lq)
    float al[4];
#pragma unroll
    for (int r = 0; r < 4; ++r) {
      float rm = fmaxf(fmaxf(scf[0][r], scf[1][r]), fmaxf(scf[2][r], scf[3][r]));
#pragma unroll
      for (int off = 8; off > 0; off >>= 1) rm = fmaxf(rm, __shfl_xor(rm, off));
      float nm = fmaxf(mrun[r], rm);
      al[r] = __expf(mrun[r] - nm);
      mrun[r] = nm;
    }
    float pv[4][4], rs[4];
#pragma unroll
    for (int r = 0; r < 4; ++r) rs[r] = 0.f;
#pragma unroll
    for (int n = 0; n < 4; ++n)
#pragma unroll
      for (int r = 0; r < 4; ++r) {
        float p = __expf(scf[n][r] - mrun[r]);
        pv[n][r] = p;
        rs[r] += p;
      }
#pragma unroll
    for (int r = 0; r < 4; ++r) {
#pragma unroll
      for (int off = 8; off > 0; off >>= 1) rs[r] += __shfl_xor(rs[r], off);
      lrun[r] = lrun[r] * al[r] + rs[r];
    }
#pragma unroll
    for (int n = 0; n < 8; ++n)
#pragma unroll
      for (int r = 0; r < 4; ++r) o[n][r] *= al[r];
    // P -> wave-private LDS (swizzled), re-read as MFMA A-fragments
#pragma unroll
    for (int n = 0; n < 4; ++n)
#pragma unroll
      for (int r = 0; r < 4; ++r) {
        int prow = lq * 4 + r;
        *(bf16_t*)(sPw + prow * 128 + (((n * 16 + lr) * 2) ^ ((prow & 7) << 4))) =
            (bf16_t)pv[n][r];
      }
#pragma unroll
    for (int kk = 0; kk < 2; ++kk) {
      bf16x8 pa = *(const bf16x8*)(sPw + lr * 128 + ((kk * 64 + lq * 16) ^ swz));
#pragma unroll
      for (int n = 0; n < 8; ++n) {
        bf16x8 vb = *(const bf16x8*)(sV + (n * 16 + lr) * 128 +
                                     ((kk * 64 + lq * 16) ^ swz));
        o[n] = __builtin_amdgcn_mfma_f32_16x16x32_bf16(pa, vb, o[n], 0, 0, 0);
      }
    }
  }
  float inv[4];
#pragma unroll
  for (int r = 0; r < 4; ++r) inv[r] = 1.0f / lrun[r];
#pragma unroll
  for (int n = 0; n < 8; ++n)
#pragma unroll
    for (int r = 0; r < 4; ++r)
      Ob[(size_t)(q0 + w * 16 + lq * 4 + r) * 4096 + h * 128 + n * 16 + lr] =
          (bf16_t)(o[n][r] * inv[r]);
}

// ---------------------------------------------------------------------------
extern "C" void kernel_launch(void* const* d_in, const int* in_sizes, int n_in,
                              void* d_out, int out_size, void* d_ws, size_t ws_size,
                              hipStream_t stream) {
  const float* hidden = (const float*)d_in[0];
  const float* mask = (const float*)d_in[1];
  const float* Wq = (const float*)d_in[2];
  const float* Wk = (const float*)d_in[3];
  const float* Wv = (const float*)d_in[4];
  const float* Wo = (const float*)d_in[5];
  float* out = (float*)d_out;
  char* ws = (char*)d_ws;

  bf16_t* hB   = (bf16_t*)(ws + 0);          //  16 MB  hidden bf16 [2048][4096]
  bf16_t* Wqt  = (bf16_t*)(ws + 16777216);   //  32 MB  Wq^T  [4096][4096]
  bf16_t* Wkvt = (bf16_t*)(ws + 50331648);   //  16 MB  Wk^T|Wv^T [2048][4096]
  bf16_t* Wot  = (bf16_t*)(ws + 67108864);   //  32 MB  Wo^T  [4096][4096]
  bf16_t* Qb   = (bf16_t*)(ws + 100663296);  //  16 MB  Q roped+scaled [2048][4096]
  bf16_t* Kb   = (bf16_t*)(ws + 117440512);  //   4 MB  K roped [2048][1024]
  bf16_t* Vb   = (bf16_t*)(ws + 121634816);  //   4 MB  V [2048][1024]
  bf16_t* Vt   = (bf16_t*)(ws + 125829120);  //   4 MB  V^T [1024][2048]
  bf16_t* Ob   = (bf16_t*)(ws + 130023424);  //  16 MB  attn out [2048][4096]
  float*  cosT = (float*)(ws + 146800640);   // 0.5 MB
  float*  sinT = (float*)(ws + 147324928);   // 0.5 MB

  cvt_bf16_kernel<<<4096, 256, 0, stream>>>(hidden, hB, 1048576);
  trcvt_kernel<<<dim3(128, 128), dim3(32, 8), 0, stream>>>(Wq, Wqt, 4096, 4096);
  trcvt_kernel<<<dim3(32, 128), dim3(32, 8), 0, stream>>>(Wk, Wkvt, 4096, 1024);
  trcvt_kernel<<<dim3(32, 128), dim3(32, 8), 0, stream>>>(Wv, Wkvt + (size_t)1024 * 4096, 4096, 1024);
  trcvt_kernel<<<dim3(128, 128), dim3(32, 8), 0, stream>>>(Wo, Wot, 4096, 4096);
  rope_tab_kernel<<<512, 256, 0, stream>>>(cosT, sinT);
  gemm_bt_kernel<0><<<768, 256, 0, stream>>>(hB, Wqt, Wkvt, cosT, sinT, Qb, Kb, Vb, nullptr);
  trb_kernel<<<dim3(32, 64), dim3(32, 8), 0, stream>>>(Vb, Vt, 2048, 1024);
  attn_kernel<<<1024, 256, 0, stream>>>(Qb, Kb, Vt, mask, Ob);
  gemm_bt_kernel<1><<<512, 256, 0, stream>>>(Ob, Wot, nullptr, nullptr, nullptr,
                                             nullptr, nullptr, nullptr, out);
}

// Round 3
// 365.017 us; speedup vs baseline: 1.0961x; 1.0961x over previous
//
#include <hip/hip_runtime.h>
#include <hip/hip_bf16.h>

typedef __bf16 bf16_t;
typedef __bf16 bf16x8 __attribute__((ext_vector_type(8)));
typedef float f32x4 __attribute__((ext_vector_type(4)));

// ---------------------------------------------------------------------------
// async global->LDS, 16B per lane (dest must be wave-uniform base + lane*16)
__device__ __forceinline__ void gload_lds16(const void* g, void* l) {
  __builtin_amdgcn_global_load_lds((const __attribute__((address_space(1))) void*)g,
                                   (__attribute__((address_space(3))) void*)l, 16, 0, 0);
}

// ---------------------------------------------------------------------------
// fp32 -> bf16 cast, 8 elements/thread
__global__ __launch_bounds__(256) void cvt_bf16_kernel(const float* __restrict__ src,
                                                       bf16_t* __restrict__ dst, int n8) {
  int i = blockIdx.x * 256 + threadIdx.x;
  if (i >= n8) return;
  const float4* s4 = (const float4*)src;
  float4 a = s4[2 * i], b = s4[2 * i + 1];
  bf16x8 o;
  o[0] = (bf16_t)a.x; o[1] = (bf16_t)a.y; o[2] = (bf16_t)a.z; o[3] = (bf16_t)a.w;
  o[4] = (bf16_t)b.x; o[5] = (bf16_t)b.y; o[6] = (bf16_t)b.z; o[7] = (bf16_t)b.w;
  *(bf16x8*)(dst + 8 * (size_t)i) = o;
}

// ---------------------------------------------------------------------------
// fp32 [R][C] -> bf16 [C][R]  (weights: store W^T so GEMM B-staging is linear)
__global__ __launch_bounds__(256) void trcvt_kernel(const float* __restrict__ src,
                                                    bf16_t* __restrict__ dst, int R, int C) {
  __shared__ float tile[32][33];
  int c0 = blockIdx.x * 32, r0 = blockIdx.y * 32;
  int tx = threadIdx.x, ty = threadIdx.y;
#pragma unroll
  for (int i = 0; i < 4; ++i)
    tile[ty + i * 8][tx] = src[(size_t)(r0 + ty + i * 8) * C + c0 + tx];
  __syncthreads();
#pragma unroll
  for (int i = 0; i < 4; ++i)
    dst[(size_t)(c0 + ty + i * 8) * R + r0 + tx] = (bf16_t)tile[tx][ty + i * 8];
}

// bf16 [R][C] -> bf16 [C][R]  (V -> V^T for the PV B-operand)
__global__ __launch_bounds__(256) void trb_kernel(const bf16_t* __restrict__ src,
                                                  bf16_t* __restrict__ dst, int R, int C) {
  __shared__ bf16_t tile[32][33];
  int c0 = blockIdx.x * 32, r0 = blockIdx.y * 32;
  int tx = threadIdx.x, ty = threadIdx.y;
#pragma unroll
  for (int i = 0; i < 4; ++i)
    tile[ty + i * 8][tx] = src[(size_t)(r0 + ty + i * 8) * C + c0 + tx];
  __syncthreads();
#pragma unroll
  for (int i = 0; i < 4; ++i)
    dst[(size_t)(c0 + ty + i * 8) * R + r0 + tx] = tile[tx][ty + i * 8];
}

// ---------------------------------------------------------------------------
// RoPE tables: cos/sin[s][d], d in [0,64), angle = s * 10000^(-d/64)
__global__ __launch_bounds__(256) void rope_tab_kernel(float* __restrict__ cosT,
                                                       float* __restrict__ sinT) {
  int i = blockIdx.x * 256 + threadIdx.x;  // 2048*64
  int s = i >> 6, d = i & 63;
  float ang = (float)s * powf(10000.0f, -(float)d * (1.0f / 64.0f));
  cosT[i] = cosf(ang);
  sinT[i] = sinf(ang);
}

// ---------------------------------------------------------------------------
// GEMM  C[M,N] = A[M,K] @ B[K,N], B given transposed (Bt[N][K], ld=K=4096).
// 128x128 tile, BK=64, 4 waves each 32x128 (full head width -> register RoPE).
// MODE 0: fused QKV projection, epilogue RoPE+scale->Qb, RoPE->Kb, ->Vb.
// MODE 1: out-projection, fp32 stores to Cout.
template <int MODE>
__global__ __launch_bounds__(256, 2) void gemm_bt_kernel(
    const bf16_t* __restrict__ A, const bf16_t* __restrict__ B0,
    const bf16_t* __restrict__ B1, const float* __restrict__ cosT,
    const float* __restrict__ sinT, bf16_t* __restrict__ Qb,
    bf16_t* __restrict__ Kb, bf16_t* __restrict__ Vb, float* __restrict__ Cout) {
  constexpr int K = 4096;
  constexpr int MT = 16;
  __shared__ alignas(16) unsigned char sAB[32768];
  unsigned char* sA = sAB;
  unsigned char* sB = sAB + 16384;
  const int bx = blockIdx.x;
  const int mt = bx % MT, nt = bx / MT;
  const int bm = mt * 128;
  const bf16_t* Bt;
  if (MODE == 0)
    Bt = (nt < 32) ? (B0 + (size_t)nt * 128 * K) : (B1 + (size_t)(nt - 32) * 128 * K);
  else
    Bt = B0 + (size_t)nt * 128 * K;

  const int t = threadIdx.x;
  const int sr = t >> 3;
  const int scol = ((t & 7) ^ (sr & 7)) * 8;
  const bf16_t* aG = A + (size_t)(bm + sr) * K + scol;
  const bf16_t* bG = Bt + (size_t)sr * K + scol;
  unsigned char* aL = sA + t * 16;
  unsigned char* bL = sB + t * 16;

  const int lane = t & 63, w = t >> 6;
  const int lr = lane & 15, lq = lane >> 4;
  const int swz = (lr & 7) << 4;

  f32x4 acc[2][8];
#pragma unroll
  for (int m = 0; m < 2; ++m)
#pragma unroll
    for (int n = 0; n < 8; ++n) acc[m][n] = f32x4{0.f, 0.f, 0.f, 0.f};

  for (int k0 = 0; k0 < K; k0 += 64) {
    __syncthreads();
#pragma unroll
    for (int p = 0; p < 4; ++p) {
      gload_lds16(aG + (size_t)(p * 32) * K + k0, aL + p * 4096);
      gload_lds16(bG + (size_t)(p * 32) * K + k0, bL + p * 4096);
    }
    __syncthreads();
#pragma unroll
    for (int kk = 0; kk < 2; ++kk) {
      bf16x8 af[2], bfr[8];
#pragma unroll
      for (int m = 0; m < 2; ++m)
        af[m] = *(const bf16x8*)(sA + (w * 32 + m * 16 + lr) * 128 +
                                 ((kk * 64 + lq * 16) ^ swz));
#pragma unroll
      for (int n = 0; n < 8; ++n)
        bfr[n] = *(const bf16x8*)(sB + (n * 16 + lr) * 128 +
                                  ((kk * 64 + lq * 16) ^ swz));
#pragma unroll
      for (int m = 0; m < 2; ++m)
#pragma unroll
        for (int n = 0; n < 8; ++n)
          acc[m][n] = __builtin_amdgcn_mfma_f32_16x16x32_bf16(af[m], bfr[n],
                                                              acc[m][n], 0, 0, 0);
    }
  }

  if (MODE == 1) {
#pragma unroll
    for (int m = 0; m < 2; ++m)
#pragma unroll
      for (int n = 0; n < 8; ++n)
#pragma unroll
        for (int r = 0; r < 4; ++r)
          Cout[(size_t)(bm + w * 32 + m * 16 + lq * 4 + r) * 4096 + nt * 128 +
               n * 16 + lr] = acc[m][n][r];
  } else {
    const bool isQ = nt < 32;
    const bool isK = (nt >= 32) && (nt < 40);
    if (isQ || isK) {
      bf16_t* dst = isQ ? Qb : Kb;
      const int ld = isQ ? 4096 : 1024;
      const int col0 = isQ ? nt * 128 : (nt - 32) * 128;
      const float qs = isQ ? 0.08838834764831845f : 1.0f;
#pragma unroll
      for (int m = 0; m < 2; ++m)
#pragma unroll
        for (int n = 0; n < 4; ++n)
#pragma unroll
          for (int r = 0; r < 4; ++r) {
            int srow = bm + w * 32 + m * 16 + lq * 4 + r;
            int d = n * 16 + lr;
            float c = cosT[srow * 64 + d], s = sinT[srow * 64 + d];
            float x1 = acc[m][n][r], x2 = acc[m][n + 4][r];
            dst[(size_t)srow * ld + col0 + d] = (bf16_t)((x1 * c - x2 * s) * qs);
            dst[(size_t)srow * ld + col0 + d + 64] = (bf16_t)((x2 * c + x1 * s) * qs);
          }
    } else {
      const int col0 = (nt - 40) * 128;
#pragma unroll
      for (int m = 0; m < 2; ++m)
#pragma unroll
        for (int n = 0; n < 8; ++n)
#pragma unroll
          for (int r = 0; r < 4; ++r)
            Vb[(size_t)(bm + w * 32 + m * 16 + lq * 4 + r) * 1024 + col0 +
               n * 16 + lr] = (bf16_t)acc[m][n][r];
    }
  }
}

// ---------------------------------------------------------------------------
// Flash attention v2: QBLK=128 (2 m-frags/wave), KVBLK=64, 2-phase prefetch
// double-buffered K/V in dynamic LDS (80KB), deferred l-reduction, setprio.
// Kb layout: [2048 s][8 kv-heads * 128] (ld=1024); Vt: [8*128 d][2048 s].
__global__ __launch_bounds__(256, 2) void attn_kernel(
    const bf16_t* __restrict__ Qb, const bf16_t* __restrict__ Kb,
    const bf16_t* __restrict__ Vt, const float* __restrict__ mask,
    bf16_t* __restrict__ Ob) {
  extern __shared__ unsigned char sMem[];
  // sK[c]: c*16384          [64 k][128 d] bf16, 256B rows, swizzled
  // sV[c]: 32768+c*16384    [128 d][64 k] bf16, 128B rows, swizzled
  // sP:    65536+w*4096+m*2048  per-wave P[16 q][64 k] swizzled
  const int bx = blockIdx.x;
  const int h = bx >> 4, qt = bx & 15;
  const int kvh = h >> 2;
  const int q0 = qt * 128;
  const int t = threadIdx.x, lane = t & 63, w = t >> 6;
  const int lr = lane & 15, lq = lane >> 4;
  const int swz = (lr & 7) << 4;

  // Q fragments in registers (RoPE'd, pre-scaled by 1/sqrt(128))
  bf16x8 qf[2][4];
#pragma unroll
  for (int m = 0; m < 2; ++m)
#pragma unroll
    for (int kk = 0; kk < 4; ++kk)
      qf[m][kk] = *(const bf16x8*)(Qb + (size_t)(q0 + w * 32 + m * 16 + lr) * 4096 +
                                   h * 128 + kk * 32 + lq * 8);

  const int srK = t >> 4;
  const int scK = ((t & 15) ^ (srK & 7)) * 8;
  const bf16_t* kG = Kb + (size_t)srK * 1024 + kvh * 128 + scK;
  const int srV = t >> 3;
  const int scV = ((t & 7) ^ (srV & 7)) * 8;
  const bf16_t* vG = Vt + (size_t)(kvh * 128 + srV) * 2048 + scV;

  auto stage = [&](int c, int kt) {
    unsigned char* kL = sMem + c * 16384 + t * 16;
    unsigned char* vL = sMem + 32768 + c * 16384 + t * 16;
#pragma unroll
    for (int p = 0; p < 4; ++p)
      gload_lds16(kG + (size_t)(kt * 64 + p * 16) * 1024, kL + p * 4096);
#pragma unroll
    for (int p = 0; p < 4; ++p)
      gload_lds16(vG + (size_t)(p * 32) * 2048 + kt * 64, vL + p * 4096);
  };

  f32x4 o[2][8];
#pragma unroll
  for (int m = 0; m < 2; ++m)
#pragma unroll
    for (int n = 0; n < 8; ++n) o[m][n] = f32x4{0.f, 0.f, 0.f, 0.f};
  float mrun[2][4], lp[2][4];
#pragma unroll
  for (int m = 0; m < 2; ++m)
#pragma unroll
    for (int r = 0; r < 4; ++r) { mrun[m][r] = -1e30f; lp[m][r] = 0.f; }

  stage(0, 0);
  __syncthreads();

  for (int kt = 0; kt < 32; ++kt) {
    const int cur = kt & 1;
    if (kt < 31) stage(cur ^ 1, kt + 1);  // prefetch next tile (overlaps compute)
    const unsigned char* sK = sMem + cur * 16384;
    const unsigned char* sV = sMem + 32768 + cur * 16384;
    unsigned char* sPw = sMem + 65536 + w * 4096;

    // S = Q K^T for both m-frags, B-fragments read once
    f32x4 scf[2][4];
#pragma unroll
    for (int m = 0; m < 2; ++m)
#pragma unroll
      for (int n = 0; n < 4; ++n) scf[m][n] = f32x4{0.f, 0.f, 0.f, 0.f};
    __builtin_amdgcn_s_setprio(1);
#pragma unroll
    for (int kk = 0; kk < 4; ++kk)
#pragma unroll
      for (int n = 0; n < 4; ++n) {
        bf16x8 b = *(const bf16x8*)(sK + (n * 16 + lr) * 256 +
                                    ((kk * 64 + lq * 16) ^ swz));
        scf[0][n] = __builtin_amdgcn_mfma_f32_16x16x32_bf16(qf[0][kk], b, scf[0][n], 0, 0, 0);
        scf[1][n] = __builtin_amdgcn_mfma_f32_16x16x32_bf16(qf[1][kk], b, scf[1][n], 0, 0, 0);
      }
    __builtin_amdgcn_s_setprio(0);

    float mk[4];
#pragma unroll
    for (int n = 0; n < 4; ++n) mk[n] = mask[kt * 64 + n * 16 + lr];

    float al[2][4];
#pragma unroll
    for (int m = 0; m < 2; ++m) {
#pragma unroll
      for (int n = 0; n < 4; ++n)
#pragma unroll
        for (int r = 0; r < 4; ++r) scf[m][n][r] += mk[n];
      // row max (row = lq*4+r, owned by 16 lanes sharing lq)
#pragma unroll
      for (int r = 0; r < 4; ++r) {
        float rm = fmaxf(fmaxf(scf[m][0][r], scf[m][1][r]),
                         fmaxf(scf[m][2][r], scf[m][3][r]));
#pragma unroll
        for (int off = 8; off > 0; off >>= 1) rm = fmaxf(rm, __shfl_xor(rm, off));
        float nm = fmaxf(mrun[m][r], rm);
        al[m][r] = __expf(mrun[m][r] - nm);
        mrun[m][r] = nm;
      }
      float ps[4] = {0.f, 0.f, 0.f, 0.f};
#pragma unroll
      for (int n = 0; n < 4; ++n)
#pragma unroll
        for (int r = 0; r < 4; ++r) {
          float p = __expf(scf[m][n][r] - mrun[m][r]);
          scf[m][n][r] = p;
          ps[r] += p;
        }
#pragma unroll
      for (int r = 0; r < 4; ++r) lp[m][r] = lp[m][r] * al[m][r] + ps[r];
      // P -> wave-private LDS (swizzled)
#pragma unroll
      for (int n = 0; n < 4; ++n)
#pragma unroll
        for (int r = 0; r < 4; ++r) {
          int prow = lq * 4 + r;
          *(bf16_t*)(sPw + m * 2048 + prow * 128 +
                     (((n * 16 + lr) * 2) ^ ((prow & 7) << 4))) = (bf16_t)scf[m][n][r];
        }
      // rescale accumulated O
#pragma unroll
      for (int n = 0; n < 8; ++n)
#pragma unroll
        for (int r = 0; r < 4; ++r) o[m][n][r] *= al[m][r];
    }

    // PV: V-fragments read once, used by both m
    bf16x8 pa[2][2];
#pragma unroll
    for (int m = 0; m < 2; ++m)
#pragma unroll
      for (int kk = 0; kk < 2; ++kk)
        pa[m][kk] = *(const bf16x8*)(sPw + m * 2048 + lr * 128 +
                                     ((kk * 64 + lq * 16) ^ swz));
    __builtin_amdgcn_s_setprio(1);
#pragma unroll
    for (int kk = 0; kk < 2; ++kk)
#pragma unroll
      for (int n = 0; n < 8; ++n) {
        bf16x8 vb = *(const bf16x8*)(sV + (n * 16 + lr) * 128 +
                                     ((kk * 64 + lq * 16) ^ swz));
        o[0][n] = __builtin_amdgcn_mfma_f32_16x16x32_bf16(pa[0][kk], vb, o[0][n], 0, 0, 0);
        o[1][n] = __builtin_amdgcn_mfma_f32_16x16x32_bf16(pa[1][kk], vb, o[1][n], 0, 0, 0);
      }
    __builtin_amdgcn_s_setprio(0);
    __syncthreads();  // drains prefetch vmcnt late; protects cur buffers
  }

  // final l: reduce per-lane partials across the 16-lane row group
  float inv[2][4];
#pragma unroll
  for (int m = 0; m < 2; ++m)
#pragma unroll
    for (int r = 0; r < 4; ++r) {
      float l = lp[m][r];
#pragma unroll
      for (int off = 8; off > 0; off >>= 1) l += __shfl_xor(l, off);
      inv[m][r] = 1.0f / l;
    }
#pragma unroll
  for (int m = 0; m < 2; ++m)
#pragma unroll
    for (int n = 0; n < 8; ++n)
#pragma unroll
      for (int r = 0; r < 4; ++r)
        Ob[(size_t)(q0 + w * 32 + m * 16 + lq * 4 + r) * 4096 + h * 128 + n * 16 + lr] =
            (bf16_t)(o[m][n][r] * inv[m][r]);
}

// ---------------------------------------------------------------------------
extern "C" void kernel_launch(void* const* d_in, const int* in_sizes, int n_in,
                              void* d_out, int out_size, void* d_ws, size_t ws_size,
                              hipStream_t stream) {
  const float* hidden = (const float*)d_in[0];
  const float* mask = (const float*)d_in[1];
  const float* Wq = (const float*)d_in[2];
  const float* Wk = (const float*)d_in[3];
  const float* Wv = (const float*)d_in[4];
  const float* Wo = (const float*)d_in[5];
  float* out = (float*)d_out;
  char* ws = (char*)d_ws;

  bf16_t* hB   = (bf16_t*)(ws + 0);          //  16 MB  hidden bf16 [2048][4096]
  bf16_t* Wqt  = (bf16_t*)(ws + 16777216);   //  32 MB  Wq^T  [4096][4096]
  bf16_t* Wkvt = (bf16_t*)(ws + 50331648);   //  16 MB  Wk^T|Wv^T [2048][4096]
  bf16_t* Wot  = (bf16_t*)(ws + 67108864);   //  32 MB  Wo^T  [4096][4096]
  bf16_t* Qb   = (bf16_t*)(ws + 100663296);  //  16 MB  Q roped+scaled [2048][4096]
  bf16_t* Kb   = (bf16_t*)(ws + 117440512);  //   4 MB  K roped [2048][1024]
  bf16_t* Vb   = (bf16_t*)(ws + 121634816);  //   4 MB  V [2048][1024]
  bf16_t* Vt   = (bf16_t*)(ws + 125829120);  //   4 MB  V^T [1024][2048]
  bf16_t* Ob   = (bf16_t*)(ws + 130023424);  //  16 MB  attn out [2048][4096]
  float*  cosT = (float*)(ws + 146800640);   // 0.5 MB
  float*  sinT = (float*)(ws + 147324928);   // 0.5 MB

  hipFuncSetAttribute((const void*)attn_kernel,
                      hipFuncAttributeMaxDynamicSharedMemorySize, 81920);

  cvt_bf16_kernel<<<4096, 256, 0, stream>>>(hidden, hB, 1048576);
  trcvt_kernel<<<dim3(128, 128), dim3(32, 8), 0, stream>>>(Wq, Wqt, 4096, 4096);
  trcvt_kernel<<<dim3(32, 128), dim3(32, 8), 0, stream>>>(Wk, Wkvt, 4096, 1024);
  trcvt_kernel<<<dim3(32, 128), dim3(32, 8), 0, stream>>>(Wv, Wkvt + (size_t)1024 * 4096, 4096, 1024);
  trcvt_kernel<<<dim3(128, 128), dim3(32, 8), 0, stream>>>(Wo, Wot, 4096, 4096);
  rope_tab_kernel<<<512, 256, 0, stream>>>(cosT, sinT);
  gemm_bt_kernel<0><<<768, 256, 0, stream>>>(hB, Wqt, Wkvt, cosT, sinT, Qb, Kb, Vb, nullptr);
  trb_kernel<<<dim3(32, 64), dim3(32, 8), 0, stream>>>(Vb, Vt, 2048, 1024);
  attn_kernel<<<512, 256, 81920, stream>>>(Qb, Kb, Vt, mask, Ob);
  gemm_bt_kernel<1><<<512, 256, 0, stream>>>(Ob, Wot, nullptr, nullptr, nullptr,
                                             nullptr, nullptr, nullptr, out);
}

// Round 4
// 352.577 us; speedup vs baseline: 1.1348x; 1.0353x over previous
//
#include <hip/hip_runtime.h>
#include <hip/hip_bf16.h>

typedef __bf16 bf16_t;
typedef __bf16 bf16x8 __attribute__((ext_vector_type(8)));
typedef float f32x4 __attribute__((ext_vector_type(4)));

// ---------------------------------------------------------------------------
// async global->LDS, 16B per lane (dest must be wave-uniform base + lane*16)
__device__ __forceinline__ void gload_lds16(const void* g, void* l) {
  __builtin_amdgcn_global_load_lds((const __attribute__((address_space(1))) void*)g,
                                   (__attribute__((address_space(3))) void*)l, 16, 0, 0);
}

// ---------------------------------------------------------------------------
// fp32 -> bf16 cast, 8 elements/thread
__global__ __launch_bounds__(256) void cvt_bf16_kernel(const float* __restrict__ src,
                                                       bf16_t* __restrict__ dst, int n8) {
  int i = blockIdx.x * 256 + threadIdx.x;
  if (i >= n8) return;
  const float4* s4 = (const float4*)src;
  float4 a = s4[2 * i], b = s4[2 * i + 1];
  bf16x8 o;
  o[0] = (bf16_t)a.x; o[1] = (bf16_t)a.y; o[2] = (bf16_t)a.z; o[3] = (bf16_t)a.w;
  o[4] = (bf16_t)b.x; o[5] = (bf16_t)b.y; o[6] = (bf16_t)b.z; o[7] = (bf16_t)b.w;
  *(bf16x8*)(dst + 8 * (size_t)i) = o;
}

// ---------------------------------------------------------------------------
// fp32 [R][C] -> bf16 [C][R]  (weights: store W^T so GEMM B-staging is linear)
__global__ __launch_bounds__(256) void trcvt_kernel(const float* __restrict__ src,
                                                    bf16_t* __restrict__ dst, int R, int C) {
  __shared__ float tile[32][33];
  int c0 = blockIdx.x * 32, r0 = blockIdx.y * 32;
  int tx = threadIdx.x, ty = threadIdx.y;
#pragma unroll
  for (int i = 0; i < 4; ++i)
    tile[ty + i * 8][tx] = src[(size_t)(r0 + ty + i * 8) * C + c0 + tx];
  __syncthreads();
#pragma unroll
  for (int i = 0; i < 4; ++i)
    dst[(size_t)(c0 + ty + i * 8) * R + r0 + tx] = (bf16_t)tile[tx][ty + i * 8];
}

// Same, but permutes dst row index within each 128-row head block so the
// proj-GEMM epilogue holds RoPE pairs (d, d+64) in one lane (ni, ni+2).
// dd bits (4,5,6) -> q bits (4,6,5).
__global__ __launch_bounds__(256) void trcvt_perm_kernel(const float* __restrict__ src,
                                                         bf16_t* __restrict__ dst, int R, int C) {
  __shared__ float tile[32][33];
  int c0 = blockIdx.x * 32, r0 = blockIdx.y * 32;
  int tx = threadIdx.x, ty = threadIdx.y;
#pragma unroll
  for (int i = 0; i < 4; ++i)
    tile[ty + i * 8][tx] = src[(size_t)(r0 + ty + i * 8) * C + c0 + tx];
  __syncthreads();
#pragma unroll
  for (int i = 0; i < 4; ++i) {
    int rc = c0 + ty + i * 8;
    int dd = rc & 127;
    int q = (dd & 15) + ((dd & 16)) + ((dd >> 5) & 1 ? 64 : 0) + ((dd >> 6) ? 32 : 0);
    int r_out = (rc & ~127) | q;
    dst[(size_t)r_out * R + r0 + tx] = (bf16_t)tile[tx][ty + i * 8];
  }
}

// bf16 [R][C] -> bf16 [C][R]  (V -> V^T for the PV B-operand)
__global__ __launch_bounds__(256) void trb_kernel(const bf16_t* __restrict__ src,
                                                  bf16_t* __restrict__ dst, int R, int C) {
  __shared__ bf16_t tile[32][33];
  int c0 = blockIdx.x * 32, r0 = blockIdx.y * 32;
  int tx = threadIdx.x, ty = threadIdx.y;
#pragma unroll
  for (int i = 0; i < 4; ++i)
    tile[ty + i * 8][tx] = src[(size_t)(r0 + ty + i * 8) * C + c0 + tx];
  __syncthreads();
#pragma unroll
  for (int i = 0; i < 4; ++i)
    dst[(size_t)(c0 + ty + i * 8) * R + r0 + tx] = tile[tx][ty + i * 8];
}

// ---------------------------------------------------------------------------
// RoPE tables: cos/sin[s][d], d in [0,64), angle = s * 10000^(-d/64)
__global__ __launch_bounds__(256) void rope_tab_kernel(float* __restrict__ cosT,
                                                       float* __restrict__ sinT) {
  int i = blockIdx.x * 256 + threadIdx.x;  // 2048*64
  int s = i >> 6, d = i & 63;
  float ang = (float)s * powf(10000.0f, -(float)d * (1.0f / 64.0f));
  cosT[i] = cosf(ang);
  sinT[i] = sinf(ang);
}

// ---------------------------------------------------------------------------
// Projection GEMM, 256x256 tile, 8 waves (2Mx4N), BK=64, 4 phases/K-tile,
// double-buffered 128KB LDS, counted vmcnt(4), st-swizzled LDS.
// A[2048][4096] bf16, B = Wqt (perm) | Wkvt (K perm | V plain), N=6144.
// Epilogue: RoPE+scale -> Qb, RoPE -> Kb, plain -> Vb.
__global__ __launch_bounds__(512, 2) void proj_gemm_kernel(
    const bf16_t* __restrict__ A, const bf16_t* __restrict__ Wqt,
    const bf16_t* __restrict__ Wkvt, const float* __restrict__ cosT,
    const float* __restrict__ sinT, bf16_t* __restrict__ Qb,
    bf16_t* __restrict__ Kb, bf16_t* __restrict__ Vb) {
  constexpr int K = 4096;
  extern __shared__ unsigned char sMem[];
  // buf c (65536B): A: h*16384 + kk*8192 + row*64 + colb ; B: +32768 same.
  const int bx = blockIdx.x;
  const int mt = bx & 7, nt = bx >> 3;  // 8 x 24
  const int bm = mt * 256;
  const bf16_t* Btb = (nt < 16) ? (Wqt + (size_t)nt * 256 * K)
                                : (Wkvt + (size_t)(nt - 16) * 256 * K);

  const int t = threadIdx.x;  // 0..511
  // staging map: slot s = p*512 + t -> kk=p, row = t>>2, col16 = (t&3)*16
  const int rowU = t >> 2;
  const int cole = ((t & 3) * 8) ^ ((rowU & 8) ? 16 : 0);  // pre-swizzled src col
  const bf16_t* aS = A + (size_t)(bm + rowU) * K + cole;
  const bf16_t* bS = Btb + (size_t)rowU * K + cole;

  const int lane = t & 63, w = t >> 6;
  const int wm = w >> 2, wn = w & 3;
  const int lr = lane & 15, lq = lane >> 4;
  const int colb = (lq * 16) ^ ((lr & 8) ? 32 : 0);  // swizzled read col bytes

  auto stA = [&](int c, int h, int j) {
    unsigned char* d = sMem + c * 65536 + h * 16384 + t * 16;
    const bf16_t* g = aS + (size_t)h * 128 * K + j * 64;
    gload_lds16(g, d);
    gload_lds16(g + 32, d + 8192);
  };
  auto stB = [&](int c, int h, int j) {
    unsigned char* d = sMem + c * 65536 + 32768 + h * 16384 + t * 16;
    const bf16_t* g = bS + (size_t)h * 128 * K + j * 64;
    gload_lds16(g, d);
    gload_lds16(g + 32, d + 8192);
  };
  auto LA = [&](int c, int half, int mi, int kk) {
    return *(const bf16x8*)(sMem + c * 65536 + wm * 16384 + kk * 8192 +
                            (half * 64 + mi * 16 + lr) * 64 + colb);
  };
  auto LB = [&](int c, int ni, int kk) {
    return *(const bf16x8*)(sMem + c * 65536 + 32768 + (wn >> 1) * 16384 + kk * 8192 +
                            ((wn & 1) * 64 + ni * 16 + lr) * 64 + colb);
  };

  f32x4 acc[8][4];
#pragma unroll
  for (int i = 0; i < 8; ++i)
#pragma unroll
    for (int n = 0; n < 4; ++n) acc[i][n] = f32x4{0.f, 0.f, 0.f, 0.f};

  // prologue: tile0 (buf0) fully + B of tile1 (buf1); allow B(1) in flight
  stA(0, 0, 0); stA(0, 1, 0); stB(0, 0, 0); stB(0, 1, 0);
  stB(1, 0, 1); stB(1, 1, 1);
  asm volatile("s_waitcnt vmcnt(4)" ::: "memory");
  __builtin_amdgcn_s_barrier();
  __builtin_amdgcn_sched_barrier(0);

  bf16x8 af[4][2], bf[2][2], bf2[2][2];
  for (int j = 0; j < 64; ++j) {
    const int c = j & 1, cn = c ^ 1;
    const int jp1 = (j + 1 < 64) ? j + 1 : 63;
    const int jp2 = (j + 2 < 64) ? j + 2 : 63;
    // ---- ph0: read A-half0 + B ni0/1; stage A0(j+1); MFMA m0 x n0
#pragma unroll
    for (int mi = 0; mi < 4; ++mi)
#pragma unroll
      for (int kk = 0; kk < 2; ++kk) af[mi][kk] = LA(c, 0, mi, kk);
#pragma unroll
    for (int ni = 0; ni < 2; ++ni)
#pragma unroll
      for (int kk = 0; kk < 2; ++kk) bf[ni][kk] = LB(c, ni, kk);
    stA(cn, 0, jp1);
    __builtin_amdgcn_s_barrier();
    __builtin_amdgcn_sched_barrier(0);
    __builtin_amdgcn_s_setprio(1);
#pragma unroll
    for (int kk = 0; kk < 2; ++kk)
#pragma unroll
      for (int mi = 0; mi < 4; ++mi)
#pragma unroll
        for (int ni = 0; ni < 2; ++ni)
          acc[mi][ni] = __builtin_amdgcn_mfma_f32_16x16x32_bf16(af[mi][kk], bf[ni][kk],
                                                                acc[mi][ni], 0, 0, 0);
    __builtin_amdgcn_s_setprio(0);
    __builtin_amdgcn_sched_barrier(0);
    __builtin_amdgcn_s_barrier();
    // ---- ph1: read B ni2/3; stage A1(j+1); MFMA m0 x n1
#pragma unroll
    for (int ni = 0; ni < 2; ++ni)
#pragma unroll
      for (int kk = 0; kk < 2; ++kk) bf2[ni][kk] = LB(c, 2 + ni, kk);
    stA(cn, 1, jp1);
    __builtin_amdgcn_s_barrier();
    __builtin_amdgcn_sched_barrier(0);
    __builtin_amdgcn_s_setprio(1);
#pragma unroll
    for (int kk = 0; kk < 2; ++kk)
#pragma unroll
      for (int mi = 0; mi < 4; ++mi)
#pragma unroll
        for (int ni = 0; ni < 2; ++ni)
          acc[mi][2 + ni] = __builtin_amdgcn_mfma_f32_16x16x32_bf16(af[mi][kk], bf2[ni][kk],
                                                                    acc[mi][2 + ni], 0, 0, 0);
    __builtin_amdgcn_s_setprio(0);
    __builtin_amdgcn_sched_barrier(0);
    __builtin_amdgcn_s_barrier();
    // ---- ph2: read A-half1; stage B0(j+2); MFMA m1 x n1
#pragma unroll
    for (int mi = 0; mi < 4; ++mi)
#pragma unroll
      for (int kk = 0; kk < 2; ++kk) af[mi][kk] = LA(c, 1, mi, kk);
    stB(c, 0, jp2);
    __builtin_amdgcn_s_barrier();
    __builtin_amdgcn_sched_barrier(0);
    __builtin_amdgcn_s_setprio(1);
#pragma unroll
    for (int kk = 0; kk < 2; ++kk)
#pragma unroll
      for (int mi = 0; mi < 4; ++mi)
#pragma unroll
        for (int ni = 0; ni < 2; ++ni)
          acc[4 + mi][2 + ni] = __builtin_amdgcn_mfma_f32_16x16x32_bf16(
              af[mi][kk], bf2[ni][kk], acc[4 + mi][2 + ni], 0, 0, 0);
    __builtin_amdgcn_s_setprio(0);
    __builtin_amdgcn_sched_barrier(0);
    __builtin_amdgcn_s_barrier();
    // ---- ph3: stage B1(j+2); checkpoint vmcnt(4); MFMA m1 x n0
    stB(c, 1, jp2);
    asm volatile("s_waitcnt vmcnt(4)" ::: "memory");
    __builtin_amdgcn_s_barrier();
    __builtin_amdgcn_sched_barrier(0);
    __builtin_amdgcn_s_setprio(1);
#pragma unroll
    for (int kk = 0; kk < 2; ++kk)
#pragma unroll
      for (int mi = 0; mi < 4; ++mi)
#pragma unroll
        for (int ni = 0; ni < 2; ++ni)
          acc[4 + mi][ni] = __builtin_amdgcn_mfma_f32_16x16x32_bf16(
              af[mi][kk], bf[ni][kk], acc[4 + mi][ni], 0, 0, 0);
    __builtin_amdgcn_s_setprio(0);
    __builtin_amdgcn_sched_barrier(0);
    __builtin_amdgcn_s_barrier();
  }

  // ---- epilogue. rows: bm + wm*128 + half*64 + mi*16 + lq*4 + r
  // cols: nt*256 + wn*64 + ni*16 + lr  (Q/K cols are head-dim-permuted)
  if (nt < 20) {
    const bool isQ = nt < 16;
    bf16_t* dst = isQ ? Qb : Kb;
    const int ld = isQ ? 4096 : 1024;
    const int hh = isQ ? (nt * 2 + (wn >> 1)) : ((nt - 16) * 2 + (wn >> 1));
    const float qs = isQ ? 0.08838834764831845f : 1.0f;
    const int dbase = lr + 32 * (wn & 1);
#pragma unroll
    for (int half = 0; half < 2; ++half)
#pragma unroll
      for (int mi = 0; mi < 4; ++mi)
#pragma unroll
        for (int ni = 0; ni < 2; ++ni) {
          int d = dbase + 16 * ni;
#pragma unroll
          for (int r = 0; r < 4; ++r) {
            int srow = bm + wm * 128 + half * 64 + mi * 16 + lq * 4 + r;
            float cv = cosT[srow * 64 + d], sv = sinT[srow * 64 + d];
            float x1 = acc[half * 4 + mi][ni][r], x2 = acc[half * 4 + mi][ni + 2][r];
            dst[(size_t)srow * ld + hh * 128 + d] = (bf16_t)((x1 * cv - x2 * sv) * qs);
            dst[(size_t)srow * ld + hh * 128 + d + 64] = (bf16_t)((x2 * cv + x1 * sv) * qs);
          }
        }
  } else {
    const int col0 = (nt - 20) * 256 + wn * 64;
#pragma unroll
    for (int half = 0; half < 2; ++half)
#pragma unroll
      for (int mi = 0; mi < 4; ++mi)
#pragma unroll
        for (int ni = 0; ni < 4; ++ni)
#pragma unroll
          for (int r = 0; r < 4; ++r) {
            int srow = bm + wm * 128 + half * 64 + mi * 16 + lq * 4 + r;
            Vb[(size_t)srow * 1024 + col0 + ni * 16 + lr] =
                (bf16_t)acc[half * 4 + mi][ni][r];
          }
  }
}

// ---------------------------------------------------------------------------
// Out-projection GEMM (m97 structure): C[M,4096] = A[M,4096] @ Wot^T
__global__ __launch_bounds__(256, 2) void out_gemm_kernel(
    const bf16_t* __restrict__ A, const bf16_t* __restrict__ B0,
    float* __restrict__ Cout) {
  constexpr int K = 4096;
  constexpr int MT = 16;
  __shared__ alignas(16) unsigned char sAB[32768];
  unsigned char* sA = sAB;
  unsigned char* sB = sAB + 16384;
  const int bx = blockIdx.x;
  const int mt = bx % MT, nt = bx / MT;
  const int bm = mt * 128;
  const bf16_t* Bt = B0 + (size_t)nt * 128 * K;

  const int t = threadIdx.x;
  const int sr = t >> 3;
  const int scol = ((t & 7) ^ (sr & 7)) * 8;
  const bf16_t* aG = A + (size_t)(bm + sr) * K + scol;
  const bf16_t* bG = Bt + (size_t)sr * K + scol;
  unsigned char* aL = sA + t * 16;
  unsigned char* bL = sB + t * 16;

  const int lane = t & 63, w = t >> 6;
  const int lr = lane & 15, lq = lane >> 4;
  const int swz = (lr & 7) << 4;

  f32x4 acc[2][8];
#pragma unroll
  for (int m = 0; m < 2; ++m)
#pragma unroll
    for (int n = 0; n < 8; ++n) acc[m][n] = f32x4{0.f, 0.f, 0.f, 0.f};

  for (int k0 = 0; k0 < K; k0 += 64) {
    __syncthreads();
#pragma unroll
    for (int p = 0; p < 4; ++p) {
      gload_lds16(aG + (size_t)(p * 32) * K + k0, aL + p * 4096);
      gload_lds16(bG + (size_t)(p * 32) * K + k0, bL + p * 4096);
    }
    __syncthreads();
#pragma unroll
    for (int kk = 0; kk < 2; ++kk) {
      bf16x8 af[2], bfr[8];
#pragma unroll
      for (int m = 0; m < 2; ++m)
        af[m] = *(const bf16x8*)(sA + (w * 32 + m * 16 + lr) * 128 +
                                 ((kk * 64 + lq * 16) ^ swz));
#pragma unroll
      for (int n = 0; n < 8; ++n)
        bfr[n] = *(const bf16x8*)(sB + (n * 16 + lr) * 128 +
                                  ((kk * 64 + lq * 16) ^ swz));
#pragma unroll
      for (int m = 0; m < 2; ++m)
#pragma unroll
        for (int n = 0; n < 8; ++n)
          acc[m][n] = __builtin_amdgcn_mfma_f32_16x16x32_bf16(af[m], bfr[n],
                                                              acc[m][n], 0, 0, 0);
    }
  }
#pragma unroll
  for (int m = 0; m < 2; ++m)
#pragma unroll
    for (int n = 0; n < 8; ++n)
#pragma unroll
      for (int r = 0; r < 4; ++r)
        Cout[(size_t)(bm + w * 32 + m * 16 + lq * 4 + r) * 4096 + nt * 128 +
             n * 16 + lr] = acc[m][n][r];
}

// ---------------------------------------------------------------------------
// Flash attention: QBLK=128 (2 m-frags/wave), KVBLK=64, 2-phase prefetch
// double-buffered K/V in dynamic LDS (80KB), deferred l-reduction, setprio.
__global__ __launch_bounds__(256, 2) void attn_kernel(
    const bf16_t* __restrict__ Qb, const bf16_t* __restrict__ Kb,
    const bf16_t* __restrict__ Vt, const float* __restrict__ mask,
    bf16_t* __restrict__ Ob) {
  extern __shared__ unsigned char sMem[];
  const int bx = blockIdx.x;
  const int h = bx >> 4, qt = bx & 15;
  const int kvh = h >> 2;
  const int q0 = qt * 128;
  const int t = threadIdx.x, lane = t & 63, w = t >> 6;
  const int lr = lane & 15, lq = lane >> 4;
  const int swz = (lr & 7) << 4;

  bf16x8 qf[2][4];
#pragma unroll
  for (int m = 0; m < 2; ++m)
#pragma unroll
    for (int kk = 0; kk < 4; ++kk)
      qf[m][kk] = *(const bf16x8*)(Qb + (size_t)(q0 + w * 32 + m * 16 + lr) * 4096 +
                                   h * 128 + kk * 32 + lq * 8);

  const int srK = t >> 4;
  const int scK = ((t & 15) ^ (srK & 7)) * 8;
  const bf16_t* kG = Kb + (size_t)srK * 1024 + kvh * 128 + scK;
  const int srV = t >> 3;
  const int scV = ((t & 7) ^ (srV & 7)) * 8;
  const bf16_t* vG = Vt + (size_t)(kvh * 128 + srV) * 2048 + scV;

  auto stage = [&](int c, int kt) {
    unsigned char* kL = sMem + c * 16384 + t * 16;
    unsigned char* vL = sMem + 32768 + c * 16384 + t * 16;
#pragma unroll
    for (int p = 0; p < 4; ++p)
      gload_lds16(kG + (size_t)(kt * 64 + p * 16) * 1024, kL + p * 4096);
#pragma unroll
    for (int p = 0; p < 4; ++p)
      gload_lds16(vG + (size_t)(p * 32) * 2048 + kt * 64, vL + p * 4096);
  };

  f32x4 o[2][8];
#pragma unroll
  for (int m = 0; m < 2; ++m)
#pragma unroll
    for (int n = 0; n < 8; ++n) o[m][n] = f32x4{0.f, 0.f, 0.f, 0.f};
  float mrun[2][4], lp[2][4];
#pragma unroll
  for (int m = 0; m < 2; ++m)
#pragma unroll
    for (int r = 0; r < 4; ++r) { mrun[m][r] = -1e30f; lp[m][r] = 0.f; }

  stage(0, 0);
  __syncthreads();

  for (int kt = 0; kt < 32; ++kt) {
    const int cur = kt & 1;
    if (kt < 31) stage(cur ^ 1, kt + 1);
    const unsigned char* sK = sMem + cur * 16384;
    const unsigned char* sV = sMem + 32768 + cur * 16384;
    unsigned char* sPw = sMem + 65536 + w * 4096;

    f32x4 scf[2][4];
#pragma unroll
    for (int m = 0; m < 2; ++m)
#pragma unroll
      for (int n = 0; n < 4; ++n) scf[m][n] = f32x4{0.f, 0.f, 0.f, 0.f};
    __builtin_amdgcn_s_setprio(1);
#pragma unroll
    for (int kk = 0; kk < 4; ++kk)
#pragma unroll
      for (int n = 0; n < 4; ++n) {
        bf16x8 b = *(const bf16x8*)(sK + (n * 16 + lr) * 256 +
                                    ((kk * 64 + lq * 16) ^ swz));
        scf[0][n] = __builtin_amdgcn_mfma_f32_16x16x32_bf16(qf[0][kk], b, scf[0][n], 0, 0, 0);
        scf[1][n] = __builtin_amdgcn_mfma_f32_16x16x32_bf16(qf[1][kk], b, scf[1][n], 0, 0, 0);
      }
    __builtin_amdgcn_s_setprio(0);

    float mk[4];
#pragma unroll
    for (int n = 0; n < 4; ++n) mk[n] = mask[kt * 64 + n * 16 + lr];

    float al[2][4];
#pragma unroll
    for (int m = 0; m < 2; ++m) {
#pragma unroll
      for (int n = 0; n < 4; ++n)
#pragma unroll
        for (int r = 0; r < 4; ++r) scf[m][n][r] += mk[n];
#pragma unroll
      for (int r = 0; r < 4; ++r) {
        float rm = fmaxf(fmaxf(scf[m][0][r], scf[m][1][r]),
                         fmaxf(scf[m][2][r], scf[m][3][r]));
#pragma unroll
        for (int off = 8; off > 0; off >>= 1) rm = fmaxf(rm, __shfl_xor(rm, off));
        float nm = fmaxf(mrun[m][r], rm);
        al[m][r] = __expf(mrun[m][r] - nm);
        mrun[m][r] = nm;
      }
      float ps[4] = {0.f, 0.f, 0.f, 0.f};
#pragma unroll
      for (int n = 0; n < 4; ++n)
#pragma unroll
        for (int r = 0; r < 4; ++r) {
          float p = __expf(scf[m][n][r] - mrun[m][r]);
          scf[m][n][r] = p;
          ps[r] += p;
        }
#pragma unroll
      for (int r = 0; r < 4; ++r) lp[m][r] = lp[m][r] * al[m][r] + ps[r];
#pragma unroll
      for (int n = 0; n < 4; ++n)
#pragma unroll
        for (int r = 0; r < 4; ++r) {
          int prow = lq * 4 + r;
          *(bf16_t*)(sPw + m * 2048 + prow * 128 +
                     (((n * 16 + lr) * 2) ^ ((prow & 7) << 4))) = (bf16_t)scf[m][n][r];
        }
#pragma unroll
      for (int n = 0; n < 8; ++n)
#pragma unroll
        for (int r = 0; r < 4; ++r) o[m][n][r] *= al[m][r];
    }

    bf16x8 pa[2][2];
#pragma unroll
    for (int m = 0; m < 2; ++m)
#pragma unroll
      for (int kk = 0; kk < 2; ++kk)
        pa[m][kk] = *(const bf16x8*)(sPw + m * 2048 + lr * 128 +
                                     ((kk * 64 + lq * 16) ^ swz));
    __builtin_amdgcn_s_setprio(1);
#pragma unroll
    for (int kk = 0; kk < 2; ++kk)
#pragma unroll
      for (int n = 0; n < 8; ++n) {
        bf16x8 vb = *(const bf16x8*)(sV + (n * 16 + lr) * 128 +
                                     ((kk * 64 + lq * 16) ^ swz));
        o[0][n] = __builtin_amdgcn_mfma_f32_16x16x32_bf16(pa[0][kk], vb, o[0][n], 0, 0, 0);
        o[1][n] = __builtin_amdgcn_mfma_f32_16x16x32_bf16(pa[1][kk], vb, o[1][n], 0, 0, 0);
      }
    __builtin_amdgcn_s_setprio(0);
    __syncthreads();
  }

  float inv[2][4];
#pragma unroll
  for (int m = 0; m < 2; ++m)
#pragma unroll
    for (int r = 0; r < 4; ++r) {
      float l = lp[m][r];
#pragma unroll
      for (int off = 8; off > 0; off >>= 1) l += __shfl_xor(l, off);
      inv[m][r] = 1.0f / l;
    }
#pragma unroll
  for (int m = 0; m < 2; ++m)
#pragma unroll
    for (int n = 0; n < 8; ++n)
#pragma unroll
      for (int r = 0; r < 4; ++r)
        Ob[(size_t)(q0 + w * 32 + m * 16 + lq * 4 + r) * 4096 + h * 128 + n * 16 + lr] =
            (bf16_t)(o[m][n][r] * inv[m][r]);
}

// ---------------------------------------------------------------------------
extern "C" void kernel_launch(void* const* d_in, const int* in_sizes, int n_in,
                              void* d_out, int out_size, void* d_ws, size_t ws_size,
                              hipStream_t stream) {
  const float* hidden = (const float*)d_in[0];
  const float* mask = (const float*)d_in[1];
  const float* Wq = (const float*)d_in[2];
  const float* Wk = (const float*)d_in[3];
  const float* Wv = (const float*)d_in[4];
  const float* Wo = (const float*)d_in[5];
  float* out = (float*)d_out;
  char* ws = (char*)d_ws;

  bf16_t* hB   = (bf16_t*)(ws + 0);          //  16 MB  hidden bf16 [2048][4096]
  bf16_t* Wqt  = (bf16_t*)(ws + 16777216);   //  32 MB  Wq^T perm [4096][4096]
  bf16_t* Wkvt = (bf16_t*)(ws + 50331648);   //  16 MB  Wk^T perm | Wv^T [2048][4096]
  bf16_t* Wot  = (bf16_t*)(ws + 67108864);   //  32 MB  Wo^T  [4096][4096]
  bf16_t* Qb   = (bf16_t*)(ws + 100663296);  //  16 MB  Q roped+scaled [2048][4096]
  bf16_t* Kb   = (bf16_t*)(ws + 117440512);  //   4 MB  K roped [2048][1024]
  bf16_t* Vb   = (bf16_t*)(ws + 121634816);  //   4 MB  V [2048][1024]
  bf16_t* Vt   = (bf16_t*)(ws + 125829120);  //   4 MB  V^T [1024][2048]
  bf16_t* Ob   = (bf16_t*)(ws + 130023424);  //  16 MB  attn out [2048][4096]
  float*  cosT = (float*)(ws + 146800640);   // 0.5 MB
  float*  sinT = (float*)(ws + 147324928);   // 0.5 MB

  hipFuncSetAttribute((const void*)attn_kernel,
                      hipFuncAttributeMaxDynamicSharedMemorySize, 81920);
  hipFuncSetAttribute((const void*)proj_gemm_kernel,
                      hipFuncAttributeMaxDynamicSharedMemorySize, 131072);

  cvt_bf16_kernel<<<4096, 256, 0, stream>>>(hidden, hB, 1048576);
  trcvt_perm_kernel<<<dim3(128, 128), dim3(32, 8), 0, stream>>>(Wq, Wqt, 4096, 4096);
  trcvt_perm_kernel<<<dim3(32, 128), dim3(32, 8), 0, stream>>>(Wk, Wkvt, 4096, 1024);
  trcvt_kernel<<<dim3(32, 128), dim3(32, 8), 0, stream>>>(Wv, Wkvt + (size_t)1024 * 4096, 4096, 1024);
  trcvt_kernel<<<dim3(128, 128), dim3(32, 8), 0, stream>>>(Wo, Wot, 4096, 4096);
  rope_tab_kernel<<<512, 256, 0, stream>>>(cosT, sinT);
  proj_gemm_kernel<<<192, 512, 131072, stream>>>(hB, Wqt, Wkvt, cosT, sinT, Qb, Kb, Vb);
  trb_kernel<<<dim3(32, 64), dim3(32, 8), 0, stream>>>(Vb, Vt, 2048, 1024);
  attn_kernel<<<512, 256, 81920, stream>>>(Qb, Kb, Vt, mask, Ob);
  out_gemm_kernel<<<512, 256, 0, stream>>>(Ob, Wot, out);
}

// Round 5
// 329.201 us; speedup vs baseline: 1.2154x; 1.0710x over previous
//
#include <hip/hip_runtime.h>
#include <hip/hip_bf16.h>

typedef __bf16 bf16_t;
typedef __bf16 bf16x8 __attribute__((ext_vector_type(8)));
typedef __bf16 bf16x4 __attribute__((ext_vector_type(4)));
typedef float f32x4 __attribute__((ext_vector_type(4)));
typedef float f32x16 __attribute__((ext_vector_type(16)));

// ---------------------------------------------------------------------------
// async global->LDS, 16B per lane (dest must be wave-uniform base + lane*16)
__device__ __forceinline__ void gload_lds16(const void* g, void* l) {
  __builtin_amdgcn_global_load_lds((const __attribute__((address_space(1))) void*)g,
                                   (__attribute__((address_space(3))) void*)l, 16, 0, 0);
}

// pack two f32 -> one u32 holding 2 bf16 (lo = a, hi = b)
__device__ __forceinline__ unsigned pk_bf16(float a, float b) {
  unsigned r;
  asm("v_cvt_pk_bf16_f32 %0, %1, %2" : "=v"(r) : "v"(a), "v"(b));
  return r;
}

// ---------------------------------------------------------------------------
// fp32 -> bf16 cast, 8 elements/thread
__global__ __launch_bounds__(256) void cvt_bf16_kernel(const float* __restrict__ src,
                                                       bf16_t* __restrict__ dst, int n8) {
  int i = blockIdx.x * 256 + threadIdx.x;
  if (i >= n8) return;
  const float4* s4 = (const float4*)src;
  float4 a = s4[2 * i], b = s4[2 * i + 1];
  bf16x8 o;
  o[0] = (bf16_t)a.x; o[1] = (bf16_t)a.y; o[2] = (bf16_t)a.z; o[3] = (bf16_t)a.w;
  o[4] = (bf16_t)b.x; o[5] = (bf16_t)b.y; o[6] = (bf16_t)b.z; o[7] = (bf16_t)b.w;
  *(bf16x8*)(dst + 8 * (size_t)i) = o;
}

// ---------------------------------------------------------------------------
// fp32 [R][C] -> bf16 [C][R]  (weights: store W^T so GEMM B-staging is linear)
__global__ __launch_bounds__(256) void trcvt_kernel(const float* __restrict__ src,
                                                    bf16_t* __restrict__ dst, int R, int C) {
  __shared__ float tile[32][33];
  int c0 = blockIdx.x * 32, r0 = blockIdx.y * 32;
  int tx = threadIdx.x, ty = threadIdx.y;
#pragma unroll
  for (int i = 0; i < 4; ++i)
    tile[ty + i * 8][tx] = src[(size_t)(r0 + ty + i * 8) * C + c0 + tx];
  __syncthreads();
#pragma unroll
  for (int i = 0; i < 4; ++i)
    dst[(size_t)(c0 + ty + i * 8) * R + r0 + tx] = (bf16_t)tile[tx][ty + i * 8];
}

// Same, but permutes dst row index within each 128-row head block so the
// proj-GEMM epilogue holds RoPE pairs (d, d+64) in one lane (ni, ni+2).
// dd bits (4,5,6) -> q bits (4,6,5).
__global__ __launch_bounds__(256) void trcvt_perm_kernel(const float* __restrict__ src,
                                                         bf16_t* __restrict__ dst, int R, int C) {
  __shared__ float tile[32][33];
  int c0 = blockIdx.x * 32, r0 = blockIdx.y * 32;
  int tx = threadIdx.x, ty = threadIdx.y;
#pragma unroll
  for (int i = 0; i < 4; ++i)
    tile[ty + i * 8][tx] = src[(size_t)(r0 + ty + i * 8) * C + c0 + tx];
  __syncthreads();
#pragma unroll
  for (int i = 0; i < 4; ++i) {
    int rc = c0 + ty + i * 8;
    int dd = rc & 127;
    int q = (dd & 15) + ((dd & 16)) + ((dd >> 5) & 1 ? 64 : 0) + ((dd >> 6) ? 32 : 0);
    int r_out = (rc & ~127) | q;
    dst[(size_t)r_out * R + r0 + tx] = (bf16_t)tile[tx][ty + i * 8];
  }
}

// bf16 [R][C] -> bf16 [C][R]  (V -> V^T for the attn PV A-operand)
__global__ __launch_bounds__(256) void trb_kernel(const bf16_t* __restrict__ src,
                                                  bf16_t* __restrict__ dst, int R, int C) {
  __shared__ bf16_t tile[32][33];
  int c0 = blockIdx.x * 32, r0 = blockIdx.y * 32;
  int tx = threadIdx.x, ty = threadIdx.y;
#pragma unroll
  for (int i = 0; i < 4; ++i)
    tile[ty + i * 8][tx] = src[(size_t)(r0 + ty + i * 8) * C + c0 + tx];
  __syncthreads();
#pragma unroll
  for (int i = 0; i < 4; ++i)
    dst[(size_t)(c0 + ty + i * 8) * R + r0 + tx] = tile[tx][ty + i * 8];
}

// ---------------------------------------------------------------------------
// RoPE tables: cos/sin[s][d], d in [0,64), angle = s * 10000^(-d/64)
__global__ __launch_bounds__(256) void rope_tab_kernel(float* __restrict__ cosT,
                                                       float* __restrict__ sinT) {
  int i = blockIdx.x * 256 + threadIdx.x;  // 2048*64
  int s = i >> 6, d = i & 63;
  float ang = (float)s * powf(10000.0f, -(float)d * (1.0f / 64.0f));
  cosT[i] = cosf(ang);
  sinT[i] = sinf(ang);
}

// ---------------------------------------------------------------------------
// Projection GEMM, 256x256 tile, 8 waves (2Mx4N), BK=64, 4 phases/K-tile,
// double-buffered 128KB LDS, counted vmcnt(4), st-swizzled LDS.
__global__ __launch_bounds__(512, 2) void proj_gemm_kernel(
    const bf16_t* __restrict__ A, const bf16_t* __restrict__ Wqt,
    const bf16_t* __restrict__ Wkvt, const float* __restrict__ cosT,
    const float* __restrict__ sinT, bf16_t* __restrict__ Qb,
    bf16_t* __restrict__ Kb, bf16_t* __restrict__ Vb) {
  constexpr int K = 4096;
  extern __shared__ unsigned char sMem[];
  const int bx = blockIdx.x;
  const int mt = bx & 7, nt = bx >> 3;  // 8 x 24
  const int bm = mt * 256;
  const bf16_t* Btb = (nt < 16) ? (Wqt + (size_t)nt * 256 * K)
                                : (Wkvt + (size_t)(nt - 16) * 256 * K);

  const int t = threadIdx.x;  // 0..511
  const int rowU = t >> 2;
  const int cole = ((t & 3) * 8) ^ ((rowU & 8) ? 16 : 0);
  const bf16_t* aS = A + (size_t)(bm + rowU) * K + cole;
  const bf16_t* bS = Btb + (size_t)rowU * K + cole;

  const int lane = t & 63, w = t >> 6;
  const int wm = w >> 2, wn = w & 3;
  const int lr = lane & 15, lq = lane >> 4;
  const int colb = (lq * 16) ^ ((lr & 8) ? 32 : 0);

  auto stA = [&](int c, int h, int j) {
    unsigned char* d = sMem + c * 65536 + h * 16384 + t * 16;
    const bf16_t* g = aS + (size_t)h * 128 * K + j * 64;
    gload_lds16(g, d);
    gload_lds16(g + 32, d + 8192);
  };
  auto stB = [&](int c, int h, int j) {
    unsigned char* d = sMem + c * 65536 + 32768 + h * 16384 + t * 16;
    const bf16_t* g = bS + (size_t)h * 128 * K + j * 64;
    gload_lds16(g, d);
    gload_lds16(g + 32, d + 8192);
  };
  auto LA = [&](int c, int half, int mi, int kk) {
    return *(const bf16x8*)(sMem + c * 65536 + wm * 16384 + kk * 8192 +
                            (half * 64 + mi * 16 + lr) * 64 + colb);
  };
  auto LB = [&](int c, int ni, int kk) {
    return *(const bf16x8*)(sMem + c * 65536 + 32768 + (wn >> 1) * 16384 + kk * 8192 +
                            ((wn & 1) * 64 + ni * 16 + lr) * 64 + colb);
  };

  f32x4 acc[8][4];
#pragma unroll
  for (int i = 0; i < 8; ++i)
#pragma unroll
    for (int n = 0; n < 4; ++n) acc[i][n] = f32x4{0.f, 0.f, 0.f, 0.f};

  stA(0, 0, 0); stA(0, 1, 0); stB(0, 0, 0); stB(0, 1, 0);
  stB(1, 0, 1); stB(1, 1, 1);
  asm volatile("s_waitcnt vmcnt(4)" ::: "memory");
  __builtin_amdgcn_s_barrier();
  __builtin_amdgcn_sched_barrier(0);

  bf16x8 af[4][2], bf[2][2], bf2[2][2];
  for (int j = 0; j < 64; ++j) {
    const int c = j & 1, cn = c ^ 1;
    const int jp1 = (j + 1 < 64) ? j + 1 : 63;
    const int jp2 = (j + 2 < 64) ? j + 2 : 63;
    // ---- ph0
#pragma unroll
    for (int mi = 0; mi < 4; ++mi)
#pragma unroll
      for (int kk = 0; kk < 2; ++kk) af[mi][kk] = LA(c, 0, mi, kk);
#pragma unroll
    for (int ni = 0; ni < 2; ++ni)
#pragma unroll
      for (int kk = 0; kk < 2; ++kk) bf[ni][kk] = LB(c, ni, kk);
    stA(cn, 0, jp1);
    __builtin_amdgcn_s_barrier();
    __builtin_amdgcn_sched_barrier(0);
    __builtin_amdgcn_s_setprio(1);
#pragma unroll
    for (int kk = 0; kk < 2; ++kk)
#pragma unroll
      for (int mi = 0; mi < 4; ++mi)
#pragma unroll
        for (int ni = 0; ni < 2; ++ni)
          acc[mi][ni] = __builtin_amdgcn_mfma_f32_16x16x32_bf16(af[mi][kk], bf[ni][kk],
                                                                acc[mi][ni], 0, 0, 0);
    __builtin_amdgcn_s_setprio(0);
    __builtin_amdgcn_sched_barrier(0);
    __builtin_amdgcn_s_barrier();
    // ---- ph1
#pragma unroll
    for (int ni = 0; ni < 2; ++ni)
#pragma unroll
      for (int kk = 0; kk < 2; ++kk) bf2[ni][kk] = LB(c, 2 + ni, kk);
    stA(cn, 1, jp1);
    __builtin_amdgcn_s_barrier();
    __builtin_amdgcn_sched_barrier(0);
    __builtin_amdgcn_s_setprio(1);
#pragma unroll
    for (int kk = 0; kk < 2; ++kk)
#pragma unroll
      for (int mi = 0; mi < 4; ++mi)
#pragma unroll
        for (int ni = 0; ni < 2; ++ni)
          acc[mi][2 + ni] = __builtin_amdgcn_mfma_f32_16x16x32_bf16(af[mi][kk], bf2[ni][kk],
                                                                    acc[mi][2 + ni], 0, 0, 0);
    __builtin_amdgcn_s_setprio(0);
    __builtin_amdgcn_sched_barrier(0);
    __builtin_amdgcn_s_barrier();
    // ---- ph2
#pragma unroll
    for (int mi = 0; mi < 4; ++mi)
#pragma unroll
      for (int kk = 0; kk < 2; ++kk) af[mi][kk] = LA(c, 1, mi, kk);
    stB(c, 0, jp2);
    __builtin_amdgcn_s_barrier();
    __builtin_amdgcn_sched_barrier(0);
    __builtin_amdgcn_s_setprio(1);
#pragma unroll
    for (int kk = 0; kk < 2; ++kk)
#pragma unroll
      for (int mi = 0; mi < 4; ++mi)
#pragma unroll
        for (int ni = 0; ni < 2; ++ni)
          acc[4 + mi][2 + ni] = __builtin_amdgcn_mfma_f32_16x16x32_bf16(
              af[mi][kk], bf2[ni][kk], acc[4 + mi][2 + ni], 0, 0, 0);
    __builtin_amdgcn_s_setprio(0);
    __builtin_amdgcn_sched_barrier(0);
    __builtin_amdgcn_s_barrier();
    // ---- ph3
    stB(c, 1, jp2);
    asm volatile("s_waitcnt vmcnt(4)" ::: "memory");
    __builtin_amdgcn_s_barrier();
    __builtin_amdgcn_sched_barrier(0);
    __builtin_amdgcn_s_setprio(1);
#pragma unroll
    for (int kk = 0; kk < 2; ++kk)
#pragma unroll
      for (int mi = 0; mi < 4; ++mi)
#pragma unroll
        for (int ni = 0; ni < 2; ++ni)
          acc[4 + mi][ni] = __builtin_amdgcn_mfma_f32_16x16x32_bf16(
              af[mi][kk], bf[ni][kk], acc[4 + mi][ni], 0, 0, 0);
    __builtin_amdgcn_s_setprio(0);
    __builtin_amdgcn_sched_barrier(0);
    __builtin_amdgcn_s_barrier();
  }

  if (nt < 20) {
    const bool isQ = nt < 16;
    bf16_t* dst = isQ ? Qb : Kb;
    const int ld = isQ ? 4096 : 1024;
    const int hh = isQ ? (nt * 2 + (wn >> 1)) : ((nt - 16) * 2 + (wn >> 1));
    const float qs = isQ ? 0.08838834764831845f : 1.0f;
    const int dbase = lr + 32 * (wn & 1);
#pragma unroll
    for (int half = 0; half < 2; ++half)
#pragma unroll
      for (int mi = 0; mi < 4; ++mi)
#pragma unroll
        for (int ni = 0; ni < 2; ++ni) {
          int d = dbase + 16 * ni;
#pragma unroll
          for (int r = 0; r < 4; ++r) {
            int srow = bm + wm * 128 + half * 64 + mi * 16 + lq * 4 + r;
            float cv = cosT[srow * 64 + d], sv = sinT[srow * 64 + d];
            float x1 = acc[half * 4 + mi][ni][r], x2 = acc[half * 4 + mi][ni + 2][r];
            dst[(size_t)srow * ld + hh * 128 + d] = (bf16_t)((x1 * cv - x2 * sv) * qs);
            dst[(size_t)srow * ld + hh * 128 + d + 64] = (bf16_t)((x2 * cv + x1 * sv) * qs);
          }
        }
  } else {
    const int col0 = (nt - 20) * 256 + wn * 64;
#pragma unroll
    for (int half = 0; half < 2; ++half)
#pragma unroll
      for (int mi = 0; mi < 4; ++mi)
#pragma unroll
        for (int ni = 0; ni < 4; ++ni)
#pragma unroll
          for (int r = 0; r < 4; ++r) {
            int srow = bm + wm * 128 + half * 64 + mi * 16 + lq * 4 + r;
            Vb[(size_t)srow * 1024 + col0 + ni * 16 + lr] =
                (bf16_t)acc[half * 4 + mi][ni][r];
          }
  }
}

// ---------------------------------------------------------------------------
// Out-projection GEMM (m97 structure): C[M,4096] = A[M,4096] @ Wot^T
__global__ __launch_bounds__(256, 2) void out_gemm_kernel(
    const bf16_t* __restrict__ A, const bf16_t* __restrict__ B0,
    float* __restrict__ Cout) {
  constexpr int K = 4096;
  constexpr int MT = 16;
  __shared__ alignas(16) unsigned char sAB[32768];
  unsigned char* sA = sAB;
  unsigned char* sB = sAB + 16384;
  const int bx = blockIdx.x;
  const int mt = bx % MT, nt = bx / MT;
  const int bm = mt * 128;
  const bf16_t* Bt = B0 + (size_t)nt * 128 * K;

  const int t = threadIdx.x;
  const int sr = t >> 3;
  const int scol = ((t & 7) ^ (sr & 7)) * 8;
  const bf16_t* aG = A + (size_t)(bm + sr) * K + scol;
  const bf16_t* bG = Bt + (size_t)sr * K + scol;
  unsigned char* aL = sA + t * 16;
  unsigned char* bL = sB + t * 16;

  const int lane = t & 63, w = t >> 6;
  const int lr = lane & 15, lq = lane >> 4;
  const int swz = (lr & 7) << 4;

  f32x4 acc[2][8];
#pragma unroll
  for (int m = 0; m < 2; ++m)
#pragma unroll
    for (int n = 0; n < 8; ++n) acc[m][n] = f32x4{0.f, 0.f, 0.f, 0.f};

  for (int k0 = 0; k0 < K; k0 += 64) {
    __syncthreads();
#pragma unroll
    for (int p = 0; p < 4; ++p) {
      gload_lds16(aG + (size_t)(p * 32) * K + k0, aL + p * 4096);
      gload_lds16(bG + (size_t)(p * 32) * K + k0, bL + p * 4096);
    }
    __syncthreads();
#pragma unroll
    for (int kk = 0; kk < 2; ++kk) {
      bf16x8 af[2], bfr[8];
#pragma unroll
      for (int m = 0; m < 2; ++m)
        af[m] = *(const bf16x8*)(sA + (w * 32 + m * 16 + lr) * 128 +
                                 ((kk * 64 + lq * 16) ^ swz));
#pragma unroll
      for (int n = 0; n < 8; ++n)
        bfr[n] = *(const bf16x8*)(sB + (n * 16 + lr) * 128 +
                                  ((kk * 64 + lq * 16) ^ swz));
#pragma unroll
      for (int m = 0; m < 2; ++m)
#pragma unroll
        for (int n = 0; n < 8; ++n)
          acc[m][n] = __builtin_amdgcn_mfma_f32_16x16x32_bf16(af[m], bfr[n],
                                                              acc[m][n], 0, 0, 0);
    }
  }
#pragma unroll
  for (int m = 0; m < 2; ++m)
#pragma unroll
    for (int n = 0; n < 8; ++n)
#pragma unroll
      for (int r = 0; r < 4; ++r)
        Cout[(size_t)(bm + w * 32 + m * 16 + lq * 4 + r) * 4096 + nt * 128 +
             n * 16 + lr] = acc[m][n][r];
}

// ---------------------------------------------------------------------------
// Flash attention v3: 8 waves x 32 q-rows (block = 256 q of one head),
// swapped-operand 32x32x16 MFMA. S = mfma(K,Q): lane owns q-col = lane&31,
// kv-rows (reg&3)+8*(reg>>2)+4*hi -> softmax is lane-local (+1 shfl(32)).
// O^T = mfma(V^T, P^T): same q-col ownership -> in-lane rescale. P stays in
// registers (cvt_pk + shfl(32) repack). KVBLK=64, 2-phase prefetch dbuf LDS.
__global__ __launch_bounds__(512) void attn_kernel(
    const bf16_t* __restrict__ Qb, const bf16_t* __restrict__ Kb,
    const bf16_t* __restrict__ Vt, const float* __restrict__ mask,
    bf16_t* __restrict__ Ob) {
  extern __shared__ unsigned char sMem[];
  // sK[c]: c*16384        [64 kv][128 d] bf16, 256B rows, XOR-swizzled
  // sV[c]: 32768+c*16384  [128 d][64 kv] bf16, 128B rows, XOR-swizzled
  // sMask[c]: 65536+c*256 [64] f32
  const int bx = blockIdx.x;
  const int h = bx >> 3, qt = bx & 7;
  const int kvh = h >> 2;
  const int t = threadIdx.x, lane = t & 63, w = t >> 6;
  const int ln = lane & 31, hi = lane >> 5;
  const int q0 = qt * 256 + w * 32;
  const int swz = (ln & 7) << 4;

  // Q fragments (B-operand): lane holds q = ln, d = ds*16 + hi*8 + e
  bf16x8 qf[8];
#pragma unroll
  for (int ds = 0; ds < 8; ++ds)
    qf[ds] = *(const bf16x8*)(Qb + (size_t)(q0 + ln) * 4096 + h * 128 + ds * 16 + hi * 8);

  // staging source addresses (pre-swizzled global columns)
  const int krow = t >> 4, kg = t & 15;
  const bf16_t* kSrc = Kb + (size_t)krow * 1024 + kvh * 128 +
                       (((kg * 16) ^ ((krow & 7) << 4)) >> 1);
  const int vrow = t >> 3, vg = t & 7;
  const bf16_t* vSrc = Vt + (size_t)(kvh * 128 + vrow) * 2048 +
                       (((vg * 16) ^ ((vrow & 7) << 4)) >> 1);

  auto stage = [&](int c, int kt) {
    unsigned char* kD = sMem + c * 16384 + t * 16;
    unsigned char* vD = sMem + 32768 + c * 16384 + t * 16;
    gload_lds16(kSrc + (size_t)kt * 64 * 1024, kD);
    gload_lds16(kSrc + (size_t)(kt * 64 + 32) * 1024, kD + 8192);
    gload_lds16(vSrc + kt * 64, vD);
    gload_lds16(vSrc + (size_t)64 * 2048 + kt * 64, vD + 8192);
    if (t < 16) gload_lds16(mask + kt * 64 + t * 4, sMem + 65536 + c * 256 + t * 16);
  };

  f32x16 o[4];
#pragma unroll
  for (int db = 0; db < 4; ++db)
#pragma unroll
    for (int e = 0; e < 16; ++e) o[db][e] = 0.f;
  float mrun = -1e30f, lp = 0.f;

  stage(0, 0);
  __syncthreads();

  for (int kt = 0; kt < 32; ++kt) {
    const int c = kt & 1;
    if (kt < 31) stage(c ^ 1, kt + 1);  // prefetch overlaps compute
    const unsigned char* sK = sMem + c * 16384;
    const unsigned char* sV = sMem + 32768 + c * 16384;
    const unsigned char* sMk = sMem + 65536 + c * 256;

#pragma unroll
    for (int sub = 0; sub < 2; ++sub) {
      // ---- S = K Q^T  (rows kv, cols q)
      f32x16 s;
#pragma unroll
      for (int e = 0; e < 16; ++e) s[e] = 0.f;
      __builtin_amdgcn_s_setprio(1);
#pragma unroll
      for (int ds = 0; ds < 8; ++ds) {
        bf16x8 kf = *(const bf16x8*)(sK + (sub * 32 + ln) * 256 +
                                     ((ds * 32 + hi * 16) ^ swz));
        s = __builtin_amdgcn_mfma_f32_32x32x16_bf16(kf, qf[ds], s, 0, 0, 0);
      }
      __builtin_amdgcn_s_setprio(0);
      // ---- + mask (kv = rg*8 + (r&3) + 4*hi + 32*sub)
#pragma unroll
      for (int rg = 0; rg < 4; ++rg) {
        float4 mv = *(const float4*)(sMk + (sub * 32 + rg * 8 + 4 * hi) * 4);
        s[rg * 4 + 0] += mv.x; s[rg * 4 + 1] += mv.y;
        s[rg * 4 + 2] += mv.z; s[rg * 4 + 3] += mv.w;
      }
      // ---- online softmax, defer-max (THR=8)
      float pm = s[0];
#pragma unroll
      for (int e = 1; e < 16; ++e) pm = fmaxf(pm, s[e]);
      pm = fmaxf(pm, __shfl_xor(pm, 32));
      if (!__all(pm - mrun <= 8.0f)) {
        float nm = fmaxf(mrun, pm);
        float al = __expf(mrun - nm);
        mrun = nm;
        lp *= al;
#pragma unroll
        for (int db = 0; db < 4; ++db)
#pragma unroll
          for (int e = 0; e < 16; ++e) o[db][e] *= al;
      }
      float p[16], ps = 0.f;
#pragma unroll
      for (int e = 0; e < 16; ++e) {
        p[e] = __expf(s[e] - mrun);
        ps += p[e];
      }
      lp += ps;
      // ---- P -> bf16 B-frags (in-register, shfl(32) half-exchange) + PV
#pragma unroll
      for (int hh = 0; hh < 2; ++hh) {
        unsigned w0 = pk_bf16(p[8 * hh + 0], p[8 * hh + 1]);
        unsigned w1 = pk_bf16(p[8 * hh + 2], p[8 * hh + 3]);
        unsigned w2 = pk_bf16(p[8 * hh + 4], p[8 * hh + 5]);
        unsigned w3 = pk_bf16(p[8 * hh + 6], p[8 * hh + 7]);
        unsigned pw0 = __shfl_xor((int)w0, 32), pw1 = __shfl_xor((int)w1, 32);
        unsigned pw2 = __shfl_xor((int)w2, 32), pw3 = __shfl_xor((int)w3, 32);
        union { unsigned u[4]; bf16x8 v; } pf;
        pf.u[0] = hi ? pw2 : w0;
        pf.u[1] = hi ? pw3 : w1;
        pf.u[2] = hi ? w2 : pw0;
        pf.u[3] = hi ? w3 : pw1;
        __builtin_amdgcn_s_setprio(1);
#pragma unroll
        for (int db = 0; db < 4; ++db) {
          bf16x8 vf = *(const bf16x8*)(sV + (db * 32 + ln) * 128 +
                                       ((sub * 64 + hh * 32 + hi * 16) ^ swz));
          o[db] = __builtin_amdgcn_mfma_f32_32x32x16_bf16(vf, pf.v, o[db], 0, 0, 0);
        }
        __builtin_amdgcn_s_setprio(0);
      }
    }
    __syncthreads();  // drains prefetch; protects cur buffers
  }

  // ---- epilogue: l = own-half + partner-half; O^T regs -> Ob rows
  float l = lp + __shfl_xor(lp, 32);
  float inv = 1.0f / l;
  bf16_t* orow = Ob + (size_t)(q0 + ln) * 4096 + h * 128;
#pragma unroll
  for (int db = 0; db < 4; ++db)
#pragma unroll
    for (int rg = 0; rg < 4; ++rg) {
      bf16x4 ov;
#pragma unroll
      for (int j = 0; j < 4; ++j) ov[j] = (bf16_t)(o[db][rg * 4 + j] * inv);
      *(bf16x4*)(orow + db * 32 + rg * 8 + hi * 4) = ov;
    }
}

// ---------------------------------------------------------------------------
extern "C" void kernel_launch(void* const* d_in, const int* in_sizes, int n_in,
                              void* d_out, int out_size, void* d_ws, size_t ws_size,
                              hipStream_t stream) {
  const float* hidden = (const float*)d_in[0];
  const float* mask = (const float*)d_in[1];
  const float* Wq = (const float*)d_in[2];
  const float* Wk = (const float*)d_in[3];
  const float* Wv = (const float*)d_in[4];
  const float* Wo = (const float*)d_in[5];
  float* out = (float*)d_out;
  char* ws = (char*)d_ws;

  bf16_t* hB   = (bf16_t*)(ws + 0);          //  16 MB  hidden bf16 [2048][4096]
  bf16_t* Wqt  = (bf16_t*)(ws + 16777216);   //  32 MB  Wq^T perm [4096][4096]
  bf16_t* Wkvt = (bf16_t*)(ws + 50331648);   //  16 MB  Wk^T perm | Wv^T [2048][4096]
  bf16_t* Wot  = (bf16_t*)(ws + 67108864);   //  32 MB  Wo^T  [4096][4096]
  bf16_t* Qb   = (bf16_t*)(ws + 100663296);  //  16 MB  Q roped+scaled [2048][4096]
  bf16_t* Kb   = (bf16_t*)(ws + 117440512);  //   4 MB  K roped [2048][1024]
  bf16_t* Vb   = (bf16_t*)(ws + 121634816);  //   4 MB  V [2048][1024]
  bf16_t* Vt   = (bf16_t*)(ws + 125829120);  //   4 MB  V^T [1024][2048]
  bf16_t* Ob   = (bf16_t*)(ws + 130023424);  //  16 MB  attn out [2048][4096]
  float*  cosT = (float*)(ws + 146800640);   // 0.5 MB
  float*  sinT = (float*)(ws + 147324928);   // 0.5 MB

  hipFuncSetAttribute((const void*)attn_kernel,
                      hipFuncAttributeMaxDynamicSharedMemorySize, 66560);
  hipFuncSetAttribute((const void*)proj_gemm_kernel,
                      hipFuncAttributeMaxDynamicSharedMemorySize, 131072);

  cvt_bf16_kernel<<<4096, 256, 0, stream>>>(hidden, hB, 1048576);
  trcvt_perm_kernel<<<dim3(128, 128), dim3(32, 8), 0, stream>>>(Wq, Wqt, 4096, 4096);
  trcvt_perm_kernel<<<dim3(32, 128), dim3(32, 8), 0, stream>>>(Wk, Wkvt, 4096, 1024);
  trcvt_kernel<<<dim3(32, 128), dim3(32, 8), 0, stream>>>(Wv, Wkvt + (size_t)1024 * 4096, 4096, 1024);
  trcvt_kernel<<<dim3(128, 128), dim3(32, 8), 0, stream>>>(Wo, Wot, 4096, 4096);
  rope_tab_kernel<<<512, 256, 0, stream>>>(cosT, sinT);
  proj_gemm_kernel<<<192, 512, 131072, stream>>>(hB, Wqt, Wkvt, cosT, sinT, Qb, Kb, Vb);
  trb_kernel<<<dim3(32, 64), dim3(32, 8), 0, stream>>>(Vb, Vt, 2048, 1024);
  attn_kernel<<<256, 512, 66560, stream>>>(Qb, Kb, Vt, mask, Ob);
  out_gemm_kernel<<<512, 256, 0, stream>>>(Ob, Wot, out);
}